// Round 5
// baseline (94.636 us; speedup 1.0000x reference)
//
#include <hip/hip_runtime.h>

// TensorProduct as a dense bilinear form:
//   out[b,mo,c] = sum_{m1,m2} W[mo][m1][m2] * x1[b,m1,c] * x2[b,m2,c]
// W = dense scatter of CG_vals, rows PADDED to stride 32 (aligned s_load
// chains): W[(mo*25 + m1)*32 + m2], 80 KB in d_ws. (seg,M1,M2) triples are
// unique (validated R3/R4: plain stores pass) -> no atomics.
//
// Node 1: hipMemsetAsync zeroes W (80 KB, driver memset node).
// Node 2: scatter_w, 26 blocks x 256 — fully parallel, ~1.5 us.
// Node 3: tp_dense, thread = (mo, b, c-pair), float2 per thread. W reads are
// wave-uniform -> s_load into SGPRs (scalar pipe), x columns live in ~100
// VGPRs. __launch_bounds__(64,2) gives the allocator 256 VGPRs (no spill);
// occupancy is grid-limited (~3.1 waves/SIMD) either way.
// VALU floor: 2600 cyc/wave x 3200 waves / 1024 SIMD ~= 3.4 us.

#define NUM_M 25
#define C_DIM 128
#define W_RSTRIDE 32                         // padded m2-stride (128 B rows)
#define W_BYTES (NUM_M * NUM_M * W_RSTRIDE * 4)   // 80 KB

__global__ __launch_bounds__(256) void scatter_w(
    const float* __restrict__ cg, const int* __restrict__ M1,
    const int* __restrict__ M2, const int* __restrict__ seg,
    int nnz, float* __restrict__ W) {
    const int n = blockIdx.x * 256 + threadIdx.x;
    if (n < nnz)
        W[(seg[n] * NUM_M + M1[n]) * W_RSTRIDE + M2[n]] = cg[n];
}

__global__ __launch_bounds__(64, 2) void tp_dense(
    const float* __restrict__ x1, const float* __restrict__ x2,
    const float* __restrict__ W, float* __restrict__ out) {
    const int lane = threadIdx.x;          // 0..63 -> c-pair
    const int mo   = blockIdx.x;           // 0..24
    const int b    = blockIdx.y;           // 0..127

    const float*  __restrict__ Wm  = W + mo * (NUM_M * W_RSTRIDE);  // uniform
    const float2* __restrict__ x1b = (const float2*)x1 + b * (NUM_M * 64) + lane;
    const float2* __restrict__ x2b = (const float2*)x2 + b * (NUM_M * 64) + lane;

    // Prefetch both operand columns (50 independent dwordx2 loads, coalesced)
    float2 x1v[NUM_M], x2v[NUM_M];
#pragma unroll
    for (int m = 0; m < NUM_M; ++m) x2v[m] = x2b[m * 64];
#pragma unroll
    for (int m = 0; m < NUM_M; ++m) x1v[m] = x1b[m * 64];

    float2 acc0 = {0.f, 0.f}, acc1 = {0.f, 0.f};
    float2 acc2 = {0.f, 0.f}, acc3 = {0.f, 0.f};

#pragma unroll
    for (int m1 = 0; m1 < NUM_M; ++m1) {
        const float* __restrict__ wr = Wm + m1 * W_RSTRIDE;  // 128B-aligned row
        float2 t0, t1, t2, t3;
        t0.x = wr[24] * x2v[24].x; t0.y = wr[24] * x2v[24].y;
        t1 = {0.f, 0.f}; t2 = {0.f, 0.f}; t3 = {0.f, 0.f};
#pragma unroll
        for (int m2 = 0; m2 < 24; m2 += 4) {
            t0.x = fmaf(wr[m2 + 0], x2v[m2 + 0].x, t0.x);
            t0.y = fmaf(wr[m2 + 0], x2v[m2 + 0].y, t0.y);
            t1.x = fmaf(wr[m2 + 1], x2v[m2 + 1].x, t1.x);
            t1.y = fmaf(wr[m2 + 1], x2v[m2 + 1].y, t1.y);
            t2.x = fmaf(wr[m2 + 2], x2v[m2 + 2].x, t2.x);
            t2.y = fmaf(wr[m2 + 2], x2v[m2 + 2].y, t2.y);
            t3.x = fmaf(wr[m2 + 3], x2v[m2 + 3].x, t3.x);
            t3.y = fmaf(wr[m2 + 3], x2v[m2 + 3].y, t3.y);
        }
        float2 t;
        t.x = (t0.x + t1.x) + (t2.x + t3.x);
        t.y = (t0.y + t1.y) + (t2.y + t3.y);
        const float2 a = x1v[m1];
        switch (m1 & 3) {                  // 4 independent accumulator chains
            case 0:  acc0.x = fmaf(a.x, t.x, acc0.x); acc0.y = fmaf(a.y, t.y, acc0.y); break;
            case 1:  acc1.x = fmaf(a.x, t.x, acc1.x); acc1.y = fmaf(a.y, t.y, acc1.y); break;
            case 2:  acc2.x = fmaf(a.x, t.x, acc2.x); acc2.y = fmaf(a.y, t.y, acc2.y); break;
            default: acc3.x = fmaf(a.x, t.x, acc3.x); acc3.y = fmaf(a.y, t.y, acc3.y); break;
        }
    }

    float2 r;
    r.x = (acc0.x + acc1.x) + (acc2.x + acc3.x);
    r.y = (acc0.y + acc1.y) + (acc2.y + acc3.y);
    ((float2*)out)[(b * NUM_M + mo) * 64 + lane] = r;
}

extern "C" void kernel_launch(void* const* d_in, const int* in_sizes, int n_in,
                              void* d_out, int out_size, void* d_ws, size_t ws_size,
                              hipStream_t stream) {
    const float* x1  = (const float*)d_in[0];
    const float* x2  = (const float*)d_in[1];
    const float* cg  = (const float*)d_in[2];
    const int*   M1  = (const int*)d_in[3];
    const int*   M2  = (const int*)d_in[4];
    const int*   seg = (const int*)d_in[5];
    const int    nnz = in_sizes[2];
    float* W   = (float*)d_ws;             // 80 KB padded dense CG tensor
    float* out = (float*)d_out;

    hipMemsetAsync(W, 0, W_BYTES, stream);               // memset graph node
    scatter_w<<<(nnz + 255) / 256, 256, 0, stream>>>(cg, M1, M2, seg, nnz, W);
    dim3 grid(NUM_M, 128);                 // (mo, b); 64 threads = 64 c-pairs
    tp_dense<<<grid, 64, 0, stream>>>(x1, x2, W, out);
}